// Round 13
// baseline (281.081 us; speedup 1.0000x reference)
//
#include <hip/hip_runtime.h>
#include <hip/hip_bf16.h>

typedef unsigned short ushort_t;
typedef __bf16 bf16x8 __attribute__((ext_vector_type(8)));
typedef float f32x4 __attribute__((ext_vector_type(4)));

// Problem constants
#define E_TOT 16896
#define NT    1536
#define BGR   128
#define NPG   12
#define EPG   132
#define KD    192    // DIM_E + DIM_U
#define KDE   128    // DIM_E only (GEMM K after cg-folding)
#define KD2   384    // split-K over ef: [hi | lo | hi] x [hi | hi | lo]
#define NJ    512    // A*MID
#define NCAN  8448   // canonical edge pairs (s<d): 128 * 66

#if defined(__has_builtin)
#  if __has_builtin(__builtin_amdgcn_global_load_lds)
#    define HAS_GLL 1
#  else
#    define HAS_GLL 0
#  endif
#else
#  define HAS_GLL 0
#endif

#if HAS_GLL
__device__ __forceinline__ void gll16(const ushort_t* g, ushort_t* s) {
    __builtin_amdgcn_global_load_lds(
        (const __attribute__((address_space(1))) unsigned int*)g,
        (__attribute__((address_space(3))) unsigned int*)s, 16, 0, 0);
}
#endif

__device__ __forceinline__ float b2f(ushort_t u) {
    union { float f; unsigned int i; } c; c.i = ((unsigned int)u) << 16; return c.f;
}
__device__ __forceinline__ ushort_t f2b(float f) {
    union { float f; unsigned int i; } c; c.f = f;
    unsigned int i = c.i;
    unsigned int r = (i + 0x7FFFu + ((i >> 16) & 1u)) >> 16;
    return (ushort_t)r;
}
// fully-connected graph: local edge i=(s->d), s=i/11, d with s-skip.
__device__ __forceinline__ int rev_local(int i) {
    int s = i / 11;
    int p = i - 11 * s;
    int d = p + (p >= s ? 1 : 0);
    return d * 11 + (s < d ? s : s - 1);
}

// ---------------------------------------------------------------------------
// prep: (a) split-transpose ef-part of W_jf/W_ju to [512][384] bf16 (hi|hi|lo)
//       (b) build XeS [E][384] bf16 (hi|lo|hi) from ef only
//       (c) cg[z][g][n] = b_z[n] + gf[g]·W_z[128: ,n]  (fp32 exact)
//       (d) node linear layers -> IFF/IUU
// ---------------------------------------------------------------------------
__global__ __launch_bounds__(256) void prep_kernel(
    const float* __restrict__ Wjf, const float* __restrict__ Wju,
    const float* __restrict__ ef,  const float* __restrict__ gf,
    const float* __restrict__ bjf, const float* __restrict__ bju,
    const float* __restrict__ nf,
    const float* __restrict__ Wif, const float* __restrict__ bif,
    const float* __restrict__ Wiu, const float* __restrict__ biu,
    ushort_t* __restrict__ WtJFs, ushort_t* __restrict__ WtJUs,
    ushort_t* __restrict__ XeS, float* __restrict__ CG,
    float* __restrict__ IFF, float* __restrict__ IUU)
{
    __shared__ float Ws[128 * 32];   // node branch only (20 KB)
    __shared__ float xr[8][128];
    const int T1 = NJ * KDE;                    // 65536 weight elements
    const int NBE = (T1 + E_TOT * KDE) / 256;   // 8704
    if (blockIdx.x < (unsigned)NBE) {
        int idx = blockIdx.x * 256 + threadIdx.x;
        if (idx < T1) {
            int n = idx / KDE, k = idx - n * KDE;
            float wf = Wjf[k * NJ + n];
            ushort_t hf = f2b(wf);
            WtJFs[n * KD2 + k]       = hf;
            WtJFs[n * KD2 + 128 + k] = hf;
            WtJFs[n * KD2 + 256 + k] = f2b(wf - b2f(hf));
            float wu = Wju[k * NJ + n];
            ushort_t hu = f2b(wu);
            WtJUs[n * KD2 + k]       = hu;
            WtJUs[n * KD2 + 128 + k] = hu;
            WtJUs[n * KD2 + 256 + k] = f2b(wu - b2f(hu));
            return;
        }
        idx -= T1;
        int e = idx / KDE, k = idx - e * KDE;
        float x = ef[(size_t)e * KDE + k];
        ushort_t h = f2b(x);
        XeS[(size_t)e * KD2 + k]       = h;
        XeS[(size_t)e * KD2 + 128 + k] = f2b(x - b2f(h));
        XeS[(size_t)e * KD2 + 256 + k] = h;
        return;
    }
    if (blockIdx.x < (unsigned)(NBE + 512)) {
        // cg branch: cidx = z*65536 + g*512 + n
        int cidx = (blockIdx.x - NBE) * 256 + threadIdx.x;
        int z = cidx >> 16;
        int rem = cidx & 65535;
        int g = rem >> 9, n = rem & 511;
        const float* W = z ? Wju : Wjf;
        float acc = (z ? bju : bjf)[n];
        const float* gr = gf + g * 64;
#pragma unroll 8
        for (int k = 0; k < 64; ++k)
            acc += gr[k] * W[(size_t)(128 + k) * NJ + n];
        CG[cidx] = acc;
        return;
    }
    // node-linear branch: 8 nodes per block
    int tid = threadIdx.x;
    int n0 = (blockIdx.x - NBE - 512) * 8;
    for (int i = tid; i < 128 * 32; i += 256) {
        int k = i >> 5, j = i & 31;
        Ws[i] = (j < 16) ? Wif[k * 16 + j] : Wiu[k * 16 + (j - 16)];
    }
    for (int i = tid; i < 8 * 128; i += 256) {
        int slot = i >> 7, k = i & 127;
        int n = n0 + slot;
        xr[slot][k] = (k < 64) ? nf[(size_t)n * 64 + k] : gf[(n / NPG) * 64 + (k - 64)];
    }
    __syncthreads();
    int slot = tid >> 5, j = tid & 31;
    float acc = (j < 16) ? bif[j] : biu[j - 16];
#pragma unroll 8
    for (int k = 0; k < 128; ++k) acc += xr[slot][k] * Ws[k * 32 + j];
    int n = n0 + slot;
    if (j < 16) IFF[n * 16 + j] = acc;
    else        IUU[n * 16 + (j - 16)] = acc;
}

// ---------------------------------------------------------------------------
// GEMM (K=384): H[z][M,512] = XeS @ Wt_z + cg_z[graph].
// 128x128 tile, dbuf LDS, gll16 staging, 1 barrier/K-step, 12 K-steps.
// ---------------------------------------------------------------------------
__global__ __launch_bounds__(256) void gemm_kernel(
    const ushort_t* __restrict__ X,
    const ushort_t* __restrict__ Wt0, const ushort_t* __restrict__ Wt1,
    const float* __restrict__ CG, float* __restrict__ Hbase)
{
    __shared__ ushort_t As[2][128][32];   // 2 x 8 KB
    __shared__ ushort_t Bs[2][128][32];
    int z = blockIdx.z;
    const ushort_t* Wt = z ? Wt1 : Wt0;
    const float* cgz = CG + (size_t)z * 128 * NJ;
    float* H = Hbase + (size_t)z * E_TOT * NJ;

    int tid = threadIdx.x, lane = tid & 63, w = tid >> 6;
    int m0 = blockIdx.y * 128, n0 = blockIdx.x * 128;
    int wm = (w >> 1) * 64, wn = (w & 1) * 64;
    int r = lane & 15, q = lane >> 4;
    f32x4 acc[4][4] = {};

    int sr = w * 32 + (lane >> 2);
    int sc = (lane & 3) * 8;
    const ushort_t* xg0 = X  + (size_t)(m0 + sr)      * KD2 + sc;
    const ushort_t* xg1 = X  + (size_t)(m0 + sr + 16) * KD2 + sc;
    const ushort_t* wg0 = Wt + (size_t)(n0 + sr)      * KD2 + sc;
    const ushort_t* wg1 = Wt + (size_t)(n0 + sr + 16) * KD2 + sc;

#if HAS_GLL
    auto stage = [&](int p, int kk) {
        gll16(xg0 + kk, &As[p][w * 32][0]);
        gll16(xg1 + kk, &As[p][w * 32 + 16][0]);
        gll16(wg0 + kk, &Bs[p][w * 32][0]);
        gll16(wg1 + kk, &Bs[p][w * 32 + 16][0]);
    };
#else
    auto stage = [&](int p, int kk) {
        uint4 a0 = *(const uint4*)(xg0 + kk);
        uint4 a1 = *(const uint4*)(xg1 + kk);
        uint4 b0 = *(const uint4*)(wg0 + kk);
        uint4 b1 = *(const uint4*)(wg1 + kk);
        *(uint4*)&As[p][sr][sc]      = a0;
        *(uint4*)&As[p][sr + 16][sc] = a1;
        *(uint4*)&Bs[p][sr][sc]      = b0;
        *(uint4*)&Bs[p][sr + 16][sc] = b1;
    };
#endif

    stage(0, 0);
    int cur = 0;
    for (int kk = 0; kk < KD2; kk += 32) {
        __syncthreads();
        if (kk + 32 < KD2) stage(cur ^ 1, kk + 32);
        bf16x8 af[4], bf[4];
#pragma unroll
        for (int mi = 0; mi < 4; ++mi)
            af[mi] = *(const bf16x8*)&As[cur][wm + mi * 16 + r][q * 8];
#pragma unroll
        for (int ni = 0; ni < 4; ++ni)
            bf[ni] = *(const bf16x8*)&Bs[cur][wn + ni * 16 + r][q * 8];
#pragma unroll
        for (int mi = 0; mi < 4; ++mi)
#pragma unroll
            for (int ni = 0; ni < 4; ++ni)
                acc[mi][ni] = __builtin_amdgcn_mfma_f32_16x16x32_bf16(
                    af[mi], bf[ni], acc[mi][ni], 0, 0, 0);
        cur ^= 1;
    }
#pragma unroll
    for (int ni = 0; ni < 4; ++ni) {
        int col = n0 + wn + ni * 16 + r;
#pragma unroll
        for (int mi = 0; mi < 4; ++mi) {
            int rowb = m0 + wm + mi * 16 + q * 4;
            float* dst = H + (size_t)rowb * NJ + col;
#pragma unroll
            for (int rr = 0; rr < 4; ++rr) {
                int gg = (rowb + rr) / EPG;
                dst[(size_t)rr * NJ] = acc[mi][ni][rr] + cgz[(size_t)gg * NJ + col];
            }
        }
    }
}

// ---------------------------------------------------------------------------
// pair: canonical pairs (s<d); writes both e and rev(e) tiles.
// ---------------------------------------------------------------------------
__global__ __launch_bounds__(256) void pair_kernel(
    const float* __restrict__ Hbase, float* __restrict__ Obase)
{
    __shared__ float sA[4][16][36];
    __shared__ float sB[4][16][36];
    __shared__ float sC[4][16][20];
    const float* H = Hbase + (size_t)blockIdx.y * E_TOT * NJ;
    float* OutV = Obase + (size_t)blockIdx.y * E_TOT * 256;
    int tid = threadIdx.x, w = tid >> 6, lane = tid & 63;
    int c = blockIdx.x * 4 + w;            // canonical pair index
    int gg = c / 66, cl = c - gg * 66;
    int s = 0;
    while (cl >= 11 - s) { cl -= 11 - s; ++s; }
    int d = s + 1 + cl;                    // s < d
    int e  = gg * EPG + s * 11 + (d - 1);  // edge s->d
    int re = gg * EPG + d * 11 + s;        // edge d->s
    const float* hA = H + (size_t)e * NJ;
    const float* hB = H + (size_t)re * NJ;
    int a = lane >> 2, mseg = (lane & 3) * 8;
    float4 va0 = *(const float4*)(hA + a * 32 + mseg);
    float4 va1 = *(const float4*)(hA + a * 32 + mseg + 4);
    float4 vb0 = *(const float4*)(hB + a * 32 + mseg);
    float4 vb1 = *(const float4*)(hB + a * 32 + mseg + 4);
    *(float4*)&sA[w][a][mseg]     = va0;
    *(float4*)&sA[w][a][mseg + 4] = va1;
    *(float4*)&sB[w][a][mseg]     = vb0;
    *(float4*)&sB[w][a][mseg + 4] = vb1;
    __syncthreads();

    int b = lane & 15, a0 = (lane >> 4) * 4;
    float4 ac0 = {0,0,0,0}, ac1 = {0,0,0,0}, ac2 = {0,0,0,0}, ac3 = {0,0,0,0};
#pragma unroll
    for (int m4 = 0; m4 < 8; ++m4) {
        float4 vb = *(const float4*)&sB[w][b][m4 * 4];
        float4 x0 = *(const float4*)&sA[w][a0 + 0][m4 * 4];
        float4 x1 = *(const float4*)&sA[w][a0 + 1][m4 * 4];
        float4 x2 = *(const float4*)&sA[w][a0 + 2][m4 * 4];
        float4 x3 = *(const float4*)&sA[w][a0 + 3][m4 * 4];
        ac0.x += x0.x * vb.x; ac0.y += x0.y * vb.y; ac0.z += x0.z * vb.z; ac0.w += x0.w * vb.w;
        ac1.x += x1.x * vb.x; ac1.y += x1.y * vb.y; ac1.z += x1.z * vb.z; ac1.w += x1.w * vb.w;
        ac2.x += x2.x * vb.x; ac2.y += x2.y * vb.y; ac2.z += x2.z * vb.z; ac2.w += x2.w * vb.w;
        ac3.x += x3.x * vb.x; ac3.y += x3.y * vb.y; ac3.z += x3.z * vb.z; ac3.w += x3.w * vb.w;
    }
    float v0 = ac0.x + ac0.y + ac0.z + ac0.w;
    float v1 = ac1.x + ac1.y + ac1.z + ac1.w;
    float v2 = ac2.x + ac2.y + ac2.z + ac2.w;
    float v3 = ac3.x + ac3.y + ac3.z + ac3.w;
    float* oe = OutV + (size_t)e * 256;
    oe[(a0 + 0) * 16 + b] = v0;
    oe[(a0 + 1) * 16 + b] = v1;
    oe[(a0 + 2) * 16 + b] = v2;
    oe[(a0 + 3) * 16 + b] = v3;
    sC[w][b][a0 + 0] = v0;
    sC[w][b][a0 + 1] = v1;
    sC[w][b][a0 + 2] = v2;
    sC[w][b][a0 + 3] = v3;
    __syncthreads();
    int rr = lane >> 2, cc = (lane & 3) * 4;
    float4 t4 = { sC[w][rr][cc], sC[w][rr][cc + 1], sC[w][rr][cc + 2], sC[w][rr][cc + 3] };
    *(float4*)(OutV + (size_t)re * 256 + lane * 4) = t4;
}

// ---------------------------------------------------------------------------
// h_fl = Xe @ W_fl + b_fl   [E,32] fp32.  64 edges/block.  (unchanged — the
// flags bit-path depends on this exact summation order)
// ---------------------------------------------------------------------------
__global__ __launch_bounds__(256) void hfl_kernel(
    const float* __restrict__ ef, const float* __restrict__ gf,
    const float* __restrict__ Wfl, const float* __restrict__ bfl,
    float* __restrict__ HFL)
{
    __shared__ float Ws[KD][32];    // 24 KB
    __shared__ float xr[64][KD];    // 48 KB
    int tid = threadIdx.x;
    int e0 = blockIdx.x * 64;
    for (int i = tid; i < KD * 32; i += 256) Ws[i >> 5][i & 31] = Wfl[i];
    for (int i4 = tid; i4 < 64 * 48; i4 += 256) {
        int slot = i4 / 48, kq = i4 - slot * 48;
        int e = e0 + slot;
        float4 v;
        if (kq < 32) v = *(const float4*)&ef[(size_t)e * 128 + kq * 4];
        else         v = *(const float4*)&gf[(e / EPG) * 64 + (kq - 32) * 4];
        *(float4*)&xr[slot][kq * 4] = v;
    }
    __syncthreads();
    int j = tid & 31, es = tid >> 5;
    float acc[8];
#pragma unroll
    for (int i = 0; i < 8; ++i) acc[i] = bfl[j];
    for (int k = 0; k < KD; k += 4) {
        float w0 = Ws[k][j], w1 = Ws[k + 1][j], w2 = Ws[k + 2][j], w3 = Ws[k + 3][j];
#pragma unroll
        for (int i = 0; i < 8; ++i) {
            float4 x4 = *(const float4*)&xr[es + 8 * i][k];
            acc[i] += x4.x * w0; acc[i] += x4.y * w1;
            acc[i] += x4.z * w2; acc[i] += x4.w * w3;
        }
    }
#pragma unroll
    for (int i = 0; i < 8; ++i)
        HFL[(size_t)(e0 + es + 8 * i) * 32 + j] = acc[i];
}

// ---------------------------------------------------------------------------
// BP v5: 1024 threads (16 waves, 4/SIMD) in the spill-safe R7 code shape.
// Each 16-lane group owns edges {grp, 64+grp}; groups 0/20/40/60 (on waves
// 0/5/10/15, one per SIMD) additionally own edges 128..131 via direct
// in-loop loads (no persistent arrays => no spill path).
// ---------------------------------------------------------------------------
__global__ __launch_bounds__(1024) void bp_kernel(
    const float* __restrict__ FV, const float* __restrict__ UV,
    const float* __restrict__ HFL, const float* __restrict__ Wcls,
    const float* __restrict__ bcls, const float* __restrict__ gum,
    const float* __restrict__ IFF, const float* __restrict__ IUU,
    float* __restrict__ out)
{
    int g = blockIdx.x, tid = threadIdx.x;
    __shared__ float msg[2][EPG][16];
    __shared__ float umsg[2][EPG][16];
    __shared__ float Asum[NPG][16], Usum[NPG][16];
    __shared__ float iffs[NPG][16], iuus[NPG][16];
    __shared__ float fls[EPG];

    for (int i = tid; i < 2 * EPG * 16; i += 1024) {
        (&msg[0][0][0])[i] = 0.f;
        (&umsg[0][0][0])[i] = 0.f;
    }
    if (tid < NPG * 16) {
        float fi = IFF[g * NPG * 16 + tid];
        float ui = IUU[g * NPG * 16 + tid];
        (&iffs[0][0])[tid] = fi; (&iuus[0][0])[tid] = ui;
        (&Asum[0][0])[tid] = fi; (&Usum[0][0])[tid] = ui;
    }
    // flags fold (same arithmetic order as original flags_kernel)
    if (tid < EPG) {
        int el = tid, rel = rev_local(el);
        int e = g * EPG + el, re = g * EPG + rel;
        float l0 = bcls[0], l1 = bcls[1];
        const float* ha = HFL + (size_t)e * 32;
        const float* hb = HFL + (size_t)re * 32;
#pragma unroll
        for (int j = 0; j < 32; ++j) {
            float pp = ha[j] * hb[j];
            l0 += pp * Wcls[j * 2 + 0];
            l1 += pp * Wcls[j * 2 + 1];
        }
        int mn = min(e, re);
        l0 += gum[(size_t)mn * 2 + 0];
        l1 += gum[(size_t)mn * 2 + 1];
        fls[el] = (l0 >= l1) ? 1.0f : 0.0f;
    }

    // per-thread pair state (R7 shape: compiler rematerializes fv/uv from L2)
    int grp = tid >> 4, a = tid & 15;
    int sidx[2], ridx[2], eidx[2];
    float fv[2][16], uv[2][16], fle[2];
    const float* fvg = FV + (size_t)g * EPG * 256;
    const float* uvg = UV + (size_t)g * EPG * 256;
#pragma unroll
    for (int j = 0; j < 2; ++j) {
        int e = j * 64 + grp;
        eidx[j] = e;
        sidx[j] = e / 11;
        ridx[j] = rev_local(e);
        const float* fr = fvg + (size_t)e * 256 + a * 16;
        const float* ur = uvg + (size_t)e * 256 + a * 16;
#pragma unroll
        for (int qq = 0; qq < 4; ++qq) {
            float4 f4 = *(const float4*)(fr + qq * 4);
            float4 u4 = *(const float4*)(ur + qq * 4);
            fv[j][qq * 4 + 0] = f4.x; fv[j][qq * 4 + 1] = f4.y;
            fv[j][qq * 4 + 2] = f4.z; fv[j][qq * 4 + 3] = f4.w;
            uv[j][qq * 4 + 0] = u4.x; uv[j][qq * 4 + 1] = u4.y;
            uv[j][qq * 4 + 2] = u4.z; uv[j][qq * 4 + 3] = u4.w;
        }
    }
    // third slot: groups 0/20/40/60 -> edges 128..131 (waves 0/5/10/15)
    int x3 = (grp == 0) ? 0 : (grp == 20) ? 1 : (grp == 40) ? 2 : (grp == 60) ? 3 : -1;
    int e2 = 128 + (x3 < 0 ? 0 : x3);
    int s2 = e2 / 11, r2 = rev_local(e2);
    const float* f2p = fvg + (size_t)e2 * 256 + a * 16;
    const float* u2p = uvg + (size_t)e2 * 256 + a * 16;
    __syncthreads();
#pragma unroll
    for (int j = 0; j < 2; ++j) fle[j] = fls[eidx[j]];
    float fle2 = fls[e2];

    int cur = 0;
    for (int it = 0; it < NPG; ++it) {
        int nxt = cur ^ 1;
#pragma unroll
        for (int j = 0; j < 2; ++j) {
            int e = eidx[j], s = sidx[j], re = ridx[j];
            float t_m[16], t_u[16];
#pragma unroll
            for (int qq = 0; qq < 4; ++qq) {
                float4 av  = *(const float4*)&Asum[s][qq * 4];
                float4 mv  = *(const float4*)&msg[cur][re][qq * 4];
                float4 usv = *(const float4*)&Usum[s][qq * 4];
                float4 umv = *(const float4*)&umsg[cur][re][qq * 4];
                t_m[qq * 4 + 0] = fv[j][qq * 4 + 0] + (av.x - mv.x);
                t_m[qq * 4 + 1] = fv[j][qq * 4 + 1] + (av.y - mv.y);
                t_m[qq * 4 + 2] = fv[j][qq * 4 + 2] + (av.z - mv.z);
                t_m[qq * 4 + 3] = fv[j][qq * 4 + 3] + (av.w - mv.w);
                t_u[qq * 4 + 0] = uv[j][qq * 4 + 0] + (usv.x - umv.x);
                t_u[qq * 4 + 1] = uv[j][qq * 4 + 1] + (usv.y - umv.y);
                t_u[qq * 4 + 2] = uv[j][qq * 4 + 2] + (usv.z - umv.z);
                t_u[qq * 4 + 3] = uv[j][qq * 4 + 3] + (usv.w - umv.w);
            }
            float mx = t_m[0];
#pragma unroll
            for (int b = 1; b < 16; ++b) mx = fmaxf(mx, t_m[b]);
            float S = 0.f, num = 0.f;
#pragma unroll
            for (int b = 0; b < 16; ++b) {
                float ev = __expf(t_m[b] - mx);
                S += ev;
                num += t_u[b] * ev;
            }
            float lse = mx + __logf(S);
            float unv = num / S;
            float M2 = lse;
            M2 = fmaxf(M2, __shfl_xor(M2, 1));
            M2 = fmaxf(M2, __shfl_xor(M2, 2));
            M2 = fmaxf(M2, __shfl_xor(M2, 4));
            M2 = fmaxf(M2, __shfl_xor(M2, 8));
            float se = __expf(lse - M2);
            se += __shfl_xor(se, 1);
            se += __shfl_xor(se, 2);
            se += __shfl_xor(se, 4);
            se += __shfl_xor(se, 8);
            float LSE = M2 + __logf(se);
            msg[nxt][e][a] = (lse - LSE) * fle[j];
            umsg[nxt][e][a] = unv * fle[j];
        }
        if (x3 >= 0) {
            float t_m[16], t_u[16];
#pragma unroll
            for (int qq = 0; qq < 4; ++qq) {
                float4 fvv = *(const float4*)(f2p + qq * 4);   // in-loop load
                float4 uvv = *(const float4*)(u2p + qq * 4);
                float4 av  = *(const float4*)&Asum[s2][qq * 4];
                float4 mv  = *(const float4*)&msg[cur][r2][qq * 4];
                float4 usv = *(const float4*)&Usum[s2][qq * 4];
                float4 umv = *(const float4*)&umsg[cur][r2][qq * 4];
                t_m[qq * 4 + 0] = fvv.x + (av.x - mv.x);
                t_m[qq * 4 + 1] = fvv.y + (av.y - mv.y);
                t_m[qq * 4 + 2] = fvv.z + (av.z - mv.z);
                t_m[qq * 4 + 3] = fvv.w + (av.w - mv.w);
                t_u[qq * 4 + 0] = uvv.x + (usv.x - umv.x);
                t_u[qq * 4 + 1] = uvv.y + (usv.y - umv.y);
                t_u[qq * 4 + 2] = uvv.z + (usv.z - umv.z);
                t_u[qq * 4 + 3] = uvv.w + (usv.w - umv.w);
            }
            float mx = t_m[0];
#pragma unroll
            for (int b = 1; b < 16; ++b) mx = fmaxf(mx, t_m[b]);
            float S = 0.f, num = 0.f;
#pragma unroll
            for (int b = 0; b < 16; ++b) {
                float ev = __expf(t_m[b] - mx);
                S += ev;
                num += t_u[b] * ev;
            }
            float lse = mx + __logf(S);
            float unv = num / S;
            float M2 = lse;
            M2 = fmaxf(M2, __shfl_xor(M2, 1));
            M2 = fmaxf(M2, __shfl_xor(M2, 2));
            M2 = fmaxf(M2, __shfl_xor(M2, 4));
            M2 = fmaxf(M2, __shfl_xor(M2, 8));
            float se = __expf(lse - M2);
            se += __shfl_xor(se, 1);
            se += __shfl_xor(se, 2);
            se += __shfl_xor(se, 4);
            se += __shfl_xor(se, 8);
            float LSE = M2 + __logf(se);
            msg[nxt][e2][a] = (lse - LSE) * fle2;
            umsg[nxt][e2][a] = unv * fle2;
        }
        __syncthreads();
        if (tid < NPG * 16) {
            int n = tid >> 4, aa = tid & 15;
            float sm = 0.f, su = 0.f;
#pragma unroll
            for (int s = 0; s < NPG; ++s) {
                if (s == n) continue;
                int le = s * 11 + (n < s ? n : n - 1);
                sm += msg[nxt][le][aa];
                su += umsg[nxt][le][aa];
            }
            Asum[n][aa] = sm + iffs[n][aa];
            Usum[n][aa] = su + iuus[n][aa];
        }
        __syncthreads();
        cur = nxt;
    }
    if (tid < 16) {
        out[g * 16 + tid] = Usum[0][tid];
    }
}

// ---------------------------------------------------------------------------
extern "C" void kernel_launch(void* const* d_in, const int* in_sizes, int n_in,
                              void* d_out, int out_size, void* d_ws, size_t ws_size,
                              hipStream_t stream) {
    const float* edge_feats  = (const float*)d_in[0];
    const float* node_feats  = (const float*)d_in[1];
    const float* graph_feats = (const float*)d_in[2];
    // d_in[3] edge_feat_reflected: unused (== edge_feats[rev])
    // d_in[4] src, d_in[5] dst, d_in[6] idx_revs: unused (analytic graph structure)
    const float* gumbel      = (const float*)d_in[7];
    const float* W_jf        = (const float*)d_in[8];
    const float* b_jf        = (const float*)d_in[9];
    const float* W_if        = (const float*)d_in[10];
    const float* b_if        = (const float*)d_in[11];
    const float* W_ju        = (const float*)d_in[12];
    const float* b_ju        = (const float*)d_in[13];
    const float* W_iu        = (const float*)d_in[14];
    const float* b_iu        = (const float*)d_in[15];
    const float* W_fl        = (const float*)d_in[16];
    const float* b_fl        = (const float*)d_in[17];
    const float* W_cls       = (const float*)d_in[18];
    const float* b_cls       = (const float*)d_in[19];
    float* out = (float*)d_out;          // reference output dtype is float32
    (void)in_sizes; (void)n_in; (void)out_size; (void)ws_size;

    size_t off = 0;
    char* base = (char*)d_ws;
    auto alloc = [&](size_t bytes) {
        void* p = base + off;
        off += (bytes + 255) & ~(size_t)255;
        return p;
    };
    ushort_t* XeS   = (ushort_t*)alloc((size_t)E_TOT * KD2 * 2);  // 13.0 MB
    ushort_t* WtJFs = (ushort_t*)alloc((size_t)NJ * KD2 * 2);     // 0.39 MB
    ushort_t* WtJUs = (ushort_t*)alloc((size_t)NJ * KD2 * 2);     // 0.39 MB
    float*    CGp   = (float*)   alloc((size_t)2 * 128 * NJ * 4); // 0.52 MB
    float*    HFL   = (float*)   alloc((size_t)E_TOT * 32 * 4);   // 2.16 MB
    float*    IFFp  = (float*)   alloc((size_t)NT * 16 * 4);
    float*    IUUp  = (float*)   alloc((size_t)NT * 16 * 4);
    float*    H2    = (float*)   alloc((size_t)E_TOT * NJ * 2 * 4); // 69.2 MB
    float*    FVUV  = (float*)   alloc((size_t)E_TOT * 512 * 4);    // 34.6 MB
    float* FVv = FVUV;
    float* UVv = FVUV + (size_t)E_TOT * 256;

    const int NBE = (NJ * KDE + E_TOT * KDE) / 256;   // 8704
    const int prep_blocks = NBE + 512 + NT / 8;        // 9408

    prep_kernel<<<prep_blocks, 256, 0, stream>>>(
        W_jf, W_ju, edge_feats, graph_feats, b_jf, b_ju, node_feats,
        W_if, b_if, W_iu, b_iu, WtJFs, WtJUs, XeS, CGp, IFFp, IUUp);
    hfl_kernel<<<E_TOT / 64, 256, 0, stream>>>(edge_feats, graph_feats, W_fl, b_fl, HFL);
    gemm_kernel<<<dim3(NJ / 128, E_TOT / 128, 2), 256, 0, stream>>>(
        XeS, WtJFs, WtJUs, CGp, H2);
    pair_kernel<<<dim3(NCAN / 4, 2), 256, 0, stream>>>(H2, FVUV);
    bp_kernel<<<BGR, 1024, 0, stream>>>(FVv, UVv, HFL, W_cls, b_cls, gumbel,
                                        IFFp, IUUp, out);
}

// Round 14
// 236.048 us; speedup vs baseline: 1.1908x; 1.1908x over previous
//
#include <hip/hip_runtime.h>
#include <hip/hip_bf16.h>

typedef unsigned short ushort_t;
typedef __bf16 bf16x8 __attribute__((ext_vector_type(8)));
typedef float f32x4 __attribute__((ext_vector_type(4)));

// Problem constants
#define E_TOT 16896
#define NT    1536
#define BGR   128
#define NPG   12
#define EPG   132
#define KD    192    // DIM_E + DIM_U
#define KDE   128    // DIM_E only (GEMM K after cg-folding)
#define KD2   384    // split-K over ef: [hi | lo | hi] x [hi | hi | lo]
#define NJ    512    // A*MID
#define NCAN  8448   // canonical edge pairs (s<d): 128 * 66

#if defined(__has_builtin)
#  if __has_builtin(__builtin_amdgcn_global_load_lds)
#    define HAS_GLL 1
#  else
#    define HAS_GLL 0
#  endif
#else
#  define HAS_GLL 0
#endif

#if HAS_GLL
__device__ __forceinline__ void gll16(const ushort_t* g, ushort_t* s) {
    __builtin_amdgcn_global_load_lds(
        (const __attribute__((address_space(1))) unsigned int*)g,
        (__attribute__((address_space(3))) unsigned int*)s, 16, 0, 0);
}
#endif

__device__ __forceinline__ float b2f(ushort_t u) {
    union { float f; unsigned int i; } c; c.i = ((unsigned int)u) << 16; return c.f;
}
__device__ __forceinline__ ushort_t f2b(float f) {
    union { float f; unsigned int i; } c; c.f = f;
    unsigned int i = c.i;
    unsigned int r = (i + 0x7FFFu + ((i >> 16) & 1u)) >> 16;
    return (ushort_t)r;
}
// fully-connected graph: local edge i=(s->d), s=i/11, d with s-skip.
__device__ __forceinline__ int rev_local(int i) {
    int s = i / 11;
    int p = i - 11 * s;
    int d = p + (p >= s ? 1 : 0);
    return d * 11 + (s < d ? s : s - 1);
}

// ---------------------------------------------------------------------------
// prep v2 — coalesced:
//  Range A [0,32): W-transpose via 64x64 LDS tiles (coalesced read & write).
//  Range B [32,1088): XeS build, 8 k's/thread, float4 loads + uint4 stores.
//  Range C [1088,1600): cg[z][g][n] = b_z[n] + gf[g]·W_z[128:,n] (fp32 exact).
//  Range D [1600,1792): node linear layers -> IFF/IUU.
// ---------------------------------------------------------------------------
__global__ __launch_bounds__(256) void prep_kernel(
    const float* __restrict__ Wjf, const float* __restrict__ Wju,
    const float* __restrict__ ef,  const float* __restrict__ gf,
    const float* __restrict__ bjf, const float* __restrict__ bju,
    const float* __restrict__ nf,
    const float* __restrict__ Wif, const float* __restrict__ bif,
    const float* __restrict__ Wiu, const float* __restrict__ biu,
    ushort_t* __restrict__ WtJFs, ushort_t* __restrict__ WtJUs,
    ushort_t* __restrict__ XeS, float* __restrict__ CG,
    float* __restrict__ IFF, float* __restrict__ IUU)
{
    __shared__ union {
        float tile[64][65];                      // 16.6 KB (transpose)
        struct { float Ws[128 * 32]; float xr[8][128]; } nd;   // 20 KB (node)
    } sm;
    int tid = threadIdx.x;
    unsigned bx = blockIdx.x;

    if (bx < 32u) {
        // ---- W transpose: mat (0=jf,1=ju), 64k x 64n tile ----
        int mat = bx >> 4, t16 = bx & 15;
        int k0 = (t16 >> 3) * 64, n0 = (t16 & 7) * 64;
        const float* W = mat ? Wju : Wjf;
        ushort_t* Wt = mat ? WtJUs : WtJFs;
        int col = tid & 63, rowq = tid >> 6;
#pragma unroll
        for (int i = 0; i < 16; ++i) {
            int kk = i * 4 + rowq;
            sm.tile[kk][col] = W[(size_t)(k0 + kk) * NJ + n0 + col];
        }
        __syncthreads();
        int k = tid & 63;
#pragma unroll
        for (int i = 0; i < 16; ++i) {
            int nn = i * 4 + rowq;
            float wf = sm.tile[k][nn];
            ushort_t hf = f2b(wf);
            ushort_t lo = f2b(wf - b2f(hf));
            ushort_t* dst = Wt + (size_t)(n0 + nn) * KD2 + k0 + k;
            dst[0]   = hf;
            dst[128] = hf;
            dst[256] = lo;
        }
        return;
    }
    if (bx < 1088u) {
        // ---- XeS: thread = (e, k8) handles 8 k's ----
        int t = (int)(bx - 32u) * 256 + tid;
        int e = t >> 4, k8 = t & 15;
        const float* src = ef + (size_t)e * KDE + k8 * 8;
        float4 v0 = *(const float4*)(src);
        float4 v1 = *(const float4*)(src + 4);
        float x[8] = { v0.x, v0.y, v0.z, v0.w, v1.x, v1.y, v1.z, v1.w };
        union { ushort_t u[8]; uint4 v; } hi, lo;
#pragma unroll
        for (int i = 0; i < 8; ++i) {
            ushort_t h = f2b(x[i]);
            hi.u[i] = h;
            lo.u[i] = f2b(x[i] - b2f(h));
        }
        ushort_t* dst = XeS + (size_t)e * KD2 + k8 * 8;
        *(uint4*)(dst)       = hi.v;
        *(uint4*)(dst + 128) = lo.v;
        *(uint4*)(dst + 256) = hi.v;
        return;
    }
    if (bx < 1600u) {
        // ---- cg: cidx = z*65536 + g*512 + n ----
        int cidx = (int)(bx - 1088u) * 256 + tid;
        int z = cidx >> 16;
        int rem = cidx & 65535;
        int g = rem >> 9, n = rem & 511;
        const float* W = z ? Wju : Wjf;
        float acc = (z ? bju : bjf)[n];
        const float* gr = gf + g * 64;
#pragma unroll 8
        for (int k = 0; k < 64; ++k)
            acc += gr[k] * W[(size_t)(KDE + k) * NJ + n];
        CG[cidx] = acc;
        return;
    }
    // ---- node linear: 8 nodes per block ----
    int n0 = (int)(bx - 1600u) * 8;
    for (int i = tid; i < 128 * 32; i += 256) {
        int k = i >> 5, j = i & 31;
        sm.nd.Ws[i] = (j < 16) ? Wif[k * 16 + j] : Wiu[k * 16 + (j - 16)];
    }
    for (int i = tid; i < 8 * 128; i += 256) {
        int slot = i >> 7, k = i & 127;
        int n = n0 + slot;
        sm.nd.xr[slot][k] = (k < 64) ? nf[(size_t)n * 64 + k]
                                     : gf[(n / NPG) * 64 + (k - 64)];
    }
    __syncthreads();
    int slot = tid >> 5, j = tid & 31;
    float acc = (j < 16) ? bif[j] : biu[j - 16];
#pragma unroll 8
    for (int k = 0; k < 128; ++k) acc += sm.nd.xr[slot][k] * sm.nd.Ws[k * 32 + j];
    int n = n0 + slot;
    if (j < 16) IFF[n * 16 + j] = acc;
    else        IUU[n * 16 + (j - 16)] = acc;
}

// ---------------------------------------------------------------------------
// GEMM (K=384): H[z][M,512] = XeS @ Wt_z + cg_z[graph].
// 128x128 tile, dbuf LDS, gll16 staging, 1 barrier/K-step, 12 K-steps.
// ---------------------------------------------------------------------------
__global__ __launch_bounds__(256) void gemm_kernel(
    const ushort_t* __restrict__ X,
    const ushort_t* __restrict__ Wt0, const ushort_t* __restrict__ Wt1,
    const float* __restrict__ CG, float* __restrict__ Hbase)
{
    __shared__ ushort_t As[2][128][32];   // 2 x 8 KB
    __shared__ ushort_t Bs[2][128][32];
    int z = blockIdx.z;
    const ushort_t* Wt = z ? Wt1 : Wt0;
    const float* cgz = CG + (size_t)z * 128 * NJ;
    float* H = Hbase + (size_t)z * E_TOT * NJ;

    int tid = threadIdx.x, lane = tid & 63, w = tid >> 6;
    int m0 = blockIdx.y * 128, n0 = blockIdx.x * 128;
    int wm = (w >> 1) * 64, wn = (w & 1) * 64;
    int r = lane & 15, q = lane >> 4;
    f32x4 acc[4][4] = {};

    int sr = w * 32 + (lane >> 2);
    int sc = (lane & 3) * 8;
    const ushort_t* xg0 = X  + (size_t)(m0 + sr)      * KD2 + sc;
    const ushort_t* xg1 = X  + (size_t)(m0 + sr + 16) * KD2 + sc;
    const ushort_t* wg0 = Wt + (size_t)(n0 + sr)      * KD2 + sc;
    const ushort_t* wg1 = Wt + (size_t)(n0 + sr + 16) * KD2 + sc;

#if HAS_GLL
    auto stage = [&](int p, int kk) {
        gll16(xg0 + kk, &As[p][w * 32][0]);
        gll16(xg1 + kk, &As[p][w * 32 + 16][0]);
        gll16(wg0 + kk, &Bs[p][w * 32][0]);
        gll16(wg1 + kk, &Bs[p][w * 32 + 16][0]);
    };
#else
    auto stage = [&](int p, int kk) {
        uint4 a0 = *(const uint4*)(xg0 + kk);
        uint4 a1 = *(const uint4*)(xg1 + kk);
        uint4 b0 = *(const uint4*)(wg0 + kk);
        uint4 b1 = *(const uint4*)(wg1 + kk);
        *(uint4*)&As[p][sr][sc]      = a0;
        *(uint4*)&As[p][sr + 16][sc] = a1;
        *(uint4*)&Bs[p][sr][sc]      = b0;
        *(uint4*)&Bs[p][sr + 16][sc] = b1;
    };
#endif

    stage(0, 0);
    int cur = 0;
    for (int kk = 0; kk < KD2; kk += 32) {
        __syncthreads();
        if (kk + 32 < KD2) stage(cur ^ 1, kk + 32);
        bf16x8 af[4], bf[4];
#pragma unroll
        for (int mi = 0; mi < 4; ++mi)
            af[mi] = *(const bf16x8*)&As[cur][wm + mi * 16 + r][q * 8];
#pragma unroll
        for (int ni = 0; ni < 4; ++ni)
            bf[ni] = *(const bf16x8*)&Bs[cur][wn + ni * 16 + r][q * 8];
#pragma unroll
        for (int mi = 0; mi < 4; ++mi)
#pragma unroll
            for (int ni = 0; ni < 4; ++ni)
                acc[mi][ni] = __builtin_amdgcn_mfma_f32_16x16x32_bf16(
                    af[mi], bf[ni], acc[mi][ni], 0, 0, 0);
        cur ^= 1;
    }
#pragma unroll
    for (int ni = 0; ni < 4; ++ni) {
        int col = n0 + wn + ni * 16 + r;
#pragma unroll
        for (int mi = 0; mi < 4; ++mi) {
            int rowb = m0 + wm + mi * 16 + q * 4;
            float* dst = H + (size_t)rowb * NJ + col;
#pragma unroll
            for (int rr = 0; rr < 4; ++rr) {
                int gg = (rowb + rr) / EPG;
                dst[(size_t)rr * NJ] = acc[mi][ni][rr] + cgz[(size_t)gg * NJ + col];
            }
        }
    }
}

// ---------------------------------------------------------------------------
// pair: canonical pairs (s<d); writes both e and rev(e) tiles.
// ---------------------------------------------------------------------------
__global__ __launch_bounds__(256) void pair_kernel(
    const float* __restrict__ Hbase, float* __restrict__ Obase)
{
    __shared__ float sA[4][16][36];
    __shared__ float sB[4][16][36];
    __shared__ float sC[4][16][20];
    const float* H = Hbase + (size_t)blockIdx.y * E_TOT * NJ;
    float* OutV = Obase + (size_t)blockIdx.y * E_TOT * 256;
    int tid = threadIdx.x, w = tid >> 6, lane = tid & 63;
    int c = blockIdx.x * 4 + w;            // canonical pair index
    int gg = c / 66, cl = c - gg * 66;
    int s = 0;
    while (cl >= 11 - s) { cl -= 11 - s; ++s; }
    int d = s + 1 + cl;                    // s < d
    int e  = gg * EPG + s * 11 + (d - 1);  // edge s->d
    int re = gg * EPG + d * 11 + s;        // edge d->s
    const float* hA = H + (size_t)e * NJ;
    const float* hB = H + (size_t)re * NJ;
    int a = lane >> 2, mseg = (lane & 3) * 8;
    float4 va0 = *(const float4*)(hA + a * 32 + mseg);
    float4 va1 = *(const float4*)(hA + a * 32 + mseg + 4);
    float4 vb0 = *(const float4*)(hB + a * 32 + mseg);
    float4 vb1 = *(const float4*)(hB + a * 32 + mseg + 4);
    *(float4*)&sA[w][a][mseg]     = va0;
    *(float4*)&sA[w][a][mseg + 4] = va1;
    *(float4*)&sB[w][a][mseg]     = vb0;
    *(float4*)&sB[w][a][mseg + 4] = vb1;
    __syncthreads();

    int b = lane & 15, a0 = (lane >> 4) * 4;
    float4 ac0 = {0,0,0,0}, ac1 = {0,0,0,0}, ac2 = {0,0,0,0}, ac3 = {0,0,0,0};
#pragma unroll
    for (int m4 = 0; m4 < 8; ++m4) {
        float4 vb = *(const float4*)&sB[w][b][m4 * 4];
        float4 x0 = *(const float4*)&sA[w][a0 + 0][m4 * 4];
        float4 x1 = *(const float4*)&sA[w][a0 + 1][m4 * 4];
        float4 x2 = *(const float4*)&sA[w][a0 + 2][m4 * 4];
        float4 x3 = *(const float4*)&sA[w][a0 + 3][m4 * 4];
        ac0.x += x0.x * vb.x; ac0.y += x0.y * vb.y; ac0.z += x0.z * vb.z; ac0.w += x0.w * vb.w;
        ac1.x += x1.x * vb.x; ac1.y += x1.y * vb.y; ac1.z += x1.z * vb.z; ac1.w += x1.w * vb.w;
        ac2.x += x2.x * vb.x; ac2.y += x2.y * vb.y; ac2.z += x2.z * vb.z; ac2.w += x2.w * vb.w;
        ac3.x += x3.x * vb.x; ac3.y += x3.y * vb.y; ac3.z += x3.z * vb.z; ac3.w += x3.w * vb.w;
    }
    float v0 = ac0.x + ac0.y + ac0.z + ac0.w;
    float v1 = ac1.x + ac1.y + ac1.z + ac1.w;
    float v2 = ac2.x + ac2.y + ac2.z + ac2.w;
    float v3 = ac3.x + ac3.y + ac3.z + ac3.w;
    float* oe = OutV + (size_t)e * 256;
    oe[(a0 + 0) * 16 + b] = v0;
    oe[(a0 + 1) * 16 + b] = v1;
    oe[(a0 + 2) * 16 + b] = v2;
    oe[(a0 + 3) * 16 + b] = v3;
    sC[w][b][a0 + 0] = v0;
    sC[w][b][a0 + 1] = v1;
    sC[w][b][a0 + 2] = v2;
    sC[w][b][a0 + 3] = v3;
    __syncthreads();
    int rr = lane >> 2, cc = (lane & 3) * 4;
    float4 t4 = { sC[w][rr][cc], sC[w][rr][cc + 1], sC[w][rr][cc + 2], sC[w][rr][cc + 3] };
    *(float4*)(OutV + (size_t)re * 256 + lane * 4) = t4;
}

// ---------------------------------------------------------------------------
// h_fl = Xe @ W_fl + b_fl   [E,32] fp32.  64 edges/block.  (unchanged — the
// flags bit-path depends on this exact summation order)
// ---------------------------------------------------------------------------
__global__ __launch_bounds__(256) void hfl_kernel(
    const float* __restrict__ ef, const float* __restrict__ gf,
    const float* __restrict__ Wfl, const float* __restrict__ bfl,
    float* __restrict__ HFL)
{
    __shared__ float Ws[KD][32];    // 24 KB
    __shared__ float xr[64][KD];    // 48 KB
    int tid = threadIdx.x;
    int e0 = blockIdx.x * 64;
    for (int i = tid; i < KD * 32; i += 256) Ws[i >> 5][i & 31] = Wfl[i];
    for (int i4 = tid; i4 < 64 * 48; i4 += 256) {
        int slot = i4 / 48, kq = i4 - slot * 48;
        int e = e0 + slot;
        float4 v;
        if (kq < 32) v = *(const float4*)&ef[(size_t)e * 128 + kq * 4];
        else         v = *(const float4*)&gf[(e / EPG) * 64 + (kq - 32) * 4];
        *(float4*)&xr[slot][kq * 4] = v;
    }
    __syncthreads();
    int j = tid & 31, es = tid >> 5;
    float acc[8];
#pragma unroll
    for (int i = 0; i < 8; ++i) acc[i] = bfl[j];
    for (int k = 0; k < KD; k += 4) {
        float w0 = Ws[k][j], w1 = Ws[k + 1][j], w2 = Ws[k + 2][j], w3 = Ws[k + 3][j];
#pragma unroll
        for (int i = 0; i < 8; ++i) {
            float4 x4 = *(const float4*)&xr[es + 8 * i][k];
            acc[i] += x4.x * w0; acc[i] += x4.y * w1;
            acc[i] += x4.z * w2; acc[i] += x4.w * w3;
        }
    }
#pragma unroll
    for (int i = 0; i < 8; ++i)
        HFL[(size_t)(e0 + es + 8 * i) * 32 + j] = acc[i];
}

// ---------------------------------------------------------------------------
// BP (R12 version — proven 61 µs): 12 iterations, one block per graph,
// 704 threads, R7 spill-safe shape + flags fold.
// ---------------------------------------------------------------------------
__global__ __launch_bounds__(704, 3) void bp_kernel(
    const float* __restrict__ FV, const float* __restrict__ UV,
    const float* __restrict__ HFL, const float* __restrict__ Wcls,
    const float* __restrict__ bcls, const float* __restrict__ gum,
    const float* __restrict__ IFF, const float* __restrict__ IUU,
    float* __restrict__ out)
{
    int g = blockIdx.x, tid = threadIdx.x;
    __shared__ float msg[2][EPG][16];
    __shared__ float umsg[2][EPG][16];
    __shared__ float Asum[NPG][16], Usum[NPG][16];
    __shared__ float iffs[NPG][16], iuus[NPG][16];
    __shared__ float fls[EPG];

    for (int i = tid; i < 2 * EPG * 16; i += 704) {
        (&msg[0][0][0])[i] = 0.f;
        (&umsg[0][0][0])[i] = 0.f;
    }
    if (tid < NPG * 16) {
        float fi = IFF[g * NPG * 16 + tid];
        float ui = IUU[g * NPG * 16 + tid];
        (&iffs[0][0])[tid] = fi; (&iuus[0][0])[tid] = ui;
        (&Asum[0][0])[tid] = fi; (&Usum[0][0])[tid] = ui;
    }
    // flags fold (same arithmetic order as original flags_kernel)
    if (tid < EPG) {
        int el = tid, rel = rev_local(el);
        int e = g * EPG + el, re = g * EPG + rel;
        float l0 = bcls[0], l1 = bcls[1];
        const float* ha = HFL + (size_t)e * 32;
        const float* hb = HFL + (size_t)re * 32;
#pragma unroll
        for (int j = 0; j < 32; ++j) {
            float pp = ha[j] * hb[j];
            l0 += pp * Wcls[j * 2 + 0];
            l1 += pp * Wcls[j * 2 + 1];
        }
        int mn = min(e, re);
        l0 += gum[(size_t)mn * 2 + 0];
        l1 += gum[(size_t)mn * 2 + 1];
        fls[el] = (l0 >= l1) ? 1.0f : 0.0f;
    }

    // per-thread pair state (compiler rematerializes fv/uv from L2 — R7 form)
    int w44 = tid >> 4, a = tid & 15;
    int sidx[3], ridx[3], eidx[3];
    float fv[3][16], uv[3][16], fle[3];
    const float* fvg = FV + (size_t)g * EPG * 256;
    const float* uvg = UV + (size_t)g * EPG * 256;
#pragma unroll
    for (int j = 0; j < 3; ++j) {
        int e = j * 44 + w44;
        eidx[j] = e;
        sidx[j] = e / 11;
        ridx[j] = rev_local(e);
        const float* fr = fvg + (size_t)e * 256 + a * 16;
        const float* ur = uvg + (size_t)e * 256 + a * 16;
#pragma unroll
        for (int qq = 0; qq < 4; ++qq) {
            float4 f4 = *(const float4*)(fr + qq * 4);
            float4 u4 = *(const float4*)(ur + qq * 4);
            fv[j][qq * 4 + 0] = f4.x; fv[j][qq * 4 + 1] = f4.y;
            fv[j][qq * 4 + 2] = f4.z; fv[j][qq * 4 + 3] = f4.w;
            uv[j][qq * 4 + 0] = u4.x; uv[j][qq * 4 + 1] = u4.y;
            uv[j][qq * 4 + 2] = u4.z; uv[j][qq * 4 + 3] = u4.w;
        }
    }
    __syncthreads();
#pragma unroll
    for (int j = 0; j < 3; ++j) fle[j] = fls[eidx[j]];

    int cur = 0;
    for (int it = 0; it < NPG; ++it) {
        int nxt = cur ^ 1;
#pragma unroll
        for (int j = 0; j < 3; ++j) {
            int e = eidx[j], s = sidx[j], re = ridx[j];
            float t_m[16], t_u[16];
#pragma unroll
            for (int qq = 0; qq < 4; ++qq) {
                float4 av  = *(const float4*)&Asum[s][qq * 4];
                float4 mv  = *(const float4*)&msg[cur][re][qq * 4];
                float4 usv = *(const float4*)&Usum[s][qq * 4];
                float4 umv = *(const float4*)&umsg[cur][re][qq * 4];
                t_m[qq * 4 + 0] = fv[j][qq * 4 + 0] + (av.x - mv.x);
                t_m[qq * 4 + 1] = fv[j][qq * 4 + 1] + (av.y - mv.y);
                t_m[qq * 4 + 2] = fv[j][qq * 4 + 2] + (av.z - mv.z);
                t_m[qq * 4 + 3] = fv[j][qq * 4 + 3] + (av.w - mv.w);
                t_u[qq * 4 + 0] = uv[j][qq * 4 + 0] + (usv.x - umv.x);
                t_u[qq * 4 + 1] = uv[j][qq * 4 + 1] + (usv.y - umv.y);
                t_u[qq * 4 + 2] = uv[j][qq * 4 + 2] + (usv.z - umv.z);
                t_u[qq * 4 + 3] = uv[j][qq * 4 + 3] + (usv.w - umv.w);
            }
            float mx = t_m[0];
#pragma unroll
            for (int b = 1; b < 16; ++b) mx = fmaxf(mx, t_m[b]);
            float S = 0.f, num = 0.f;
#pragma unroll
            for (int b = 0; b < 16; ++b) {
                float ev = __expf(t_m[b] - mx);
                S += ev;
                num += t_u[b] * ev;
            }
            float lse = mx + __logf(S);
            float unv = num / S;
            float M2 = lse;
            M2 = fmaxf(M2, __shfl_xor(M2, 1));
            M2 = fmaxf(M2, __shfl_xor(M2, 2));
            M2 = fmaxf(M2, __shfl_xor(M2, 4));
            M2 = fmaxf(M2, __shfl_xor(M2, 8));
            float se = __expf(lse - M2);
            se += __shfl_xor(se, 1);
            se += __shfl_xor(se, 2);
            se += __shfl_xor(se, 4);
            se += __shfl_xor(se, 8);
            float LSE = M2 + __logf(se);
            msg[nxt][e][a] = (lse - LSE) * fle[j];
            umsg[nxt][e][a] = unv * fle[j];
        }
        __syncthreads();
        if (tid < NPG * 16) {
            int n = tid >> 4, aa = tid & 15;
            float sm = 0.f, su = 0.f;
#pragma unroll
            for (int s = 0; s < NPG; ++s) {
                if (s == n) continue;
                int le = s * 11 + (n < s ? n : n - 1);
                sm += msg[nxt][le][aa];
                su += umsg[nxt][le][aa];
            }
            Asum[n][aa] = sm + iffs[n][aa];
            Usum[n][aa] = su + iuus[n][aa];
        }
        __syncthreads();
        cur = nxt;
    }
    if (tid < 16) {
        out[g * 16 + tid] = Usum[0][tid];
    }
}

// ---------------------------------------------------------------------------
extern "C" void kernel_launch(void* const* d_in, const int* in_sizes, int n_in,
                              void* d_out, int out_size, void* d_ws, size_t ws_size,
                              hipStream_t stream) {
    const float* edge_feats  = (const float*)d_in[0];
    const float* node_feats  = (const float*)d_in[1];
    const float* graph_feats = (const float*)d_in[2];
    // d_in[3] edge_feat_reflected: unused (== edge_feats[rev])
    // d_in[4] src, d_in[5] dst, d_in[6] idx_revs: unused (analytic graph structure)
    const float* gumbel      = (const float*)d_in[7];
    const float* W_jf        = (const float*)d_in[8];
    const float* b_jf        = (const float*)d_in[9];
    const float* W_if        = (const float*)d_in[10];
    const float* b_if        = (const float*)d_in[11];
    const float* W_ju        = (const float*)d_in[12];
    const float* b_ju        = (const float*)d_in[13];
    const float* W_iu        = (const float*)d_in[14];
    const float* b_iu        = (const float*)d_in[15];
    const float* W_fl        = (const float*)d_in[16];
    const float* b_fl        = (const float*)d_in[17];
    const float* W_cls       = (const float*)d_in[18];
    const float* b_cls       = (const float*)d_in[19];
    float* out = (float*)d_out;          // reference output dtype is float32
    (void)in_sizes; (void)n_in; (void)out_size; (void)ws_size;

    size_t off = 0;
    char* base = (char*)d_ws;
    auto alloc = [&](size_t bytes) {
        void* p = base + off;
        off += (bytes + 255) & ~(size_t)255;
        return p;
    };
    ushort_t* XeS   = (ushort_t*)alloc((size_t)E_TOT * KD2 * 2);  // 13.0 MB
    ushort_t* WtJFs = (ushort_t*)alloc((size_t)NJ * KD2 * 2);     // 0.39 MB
    ushort_t* WtJUs = (ushort_t*)alloc((size_t)NJ * KD2 * 2);     // 0.39 MB
    float*    CGp   = (float*)   alloc((size_t)2 * 128 * NJ * 4); // 0.52 MB
    float*    HFL   = (float*)   alloc((size_t)E_TOT * 32 * 4);   // 2.16 MB
    float*    IFFp  = (float*)   alloc((size_t)NT * 16 * 4);
    float*    IUUp  = (float*)   alloc((size_t)NT * 16 * 4);
    float*    H2    = (float*)   alloc((size_t)E_TOT * NJ * 2 * 4); // 69.2 MB
    float*    FVUV  = (float*)   alloc((size_t)E_TOT * 512 * 4);    // 34.6 MB
    float* FVv = FVUV;
    float* UVv = FVUV + (size_t)E_TOT * 256;

    const int prep_blocks = 32 + 1056 + 512 + 192;   // 1792

    prep_kernel<<<prep_blocks, 256, 0, stream>>>(
        W_jf, W_ju, edge_feats, graph_feats, b_jf, b_ju, node_feats,
        W_if, b_if, W_iu, b_iu, WtJFs, WtJUs, XeS, CGp, IFFp, IUUp);
    hfl_kernel<<<E_TOT / 64, 256, 0, stream>>>(edge_feats, graph_feats, W_fl, b_fl, HFL);
    gemm_kernel<<<dim3(NJ / 128, E_TOT / 128, 2), 256, 0, stream>>>(
        XeS, WtJFs, WtJUs, CGp, H2);
    pair_kernel<<<dim3(NCAN / 4, 2), 256, 0, stream>>>(H2, FVUV);
    bp_kernel<<<BGR, 704, 0, stream>>>(FVv, UVv, HFL, W_cls, b_cls, gumbel,
                                       IFFp, IUUp, out);
}